// Round 10
// baseline (242.896 us; speedup 1.0000x reference)
//
#include <hip/hip_runtime.h>
#include <hip/hip_bf16.h>
#include <hip/hip_fp16.h>

// GCN 3-layer: out = A_hat @ (A_hat @ relu(A_hat @ relu(X W1)+b1 ... ) )
// R2-R8: vectorized agg, W-LDS fdot2 GEMM, f16 activations, 4B edge records,
//        device-wide scan, norm factorized into GEMM epilogue.
// R9/R10: agg = ONE DEST PER WAVE (TPD=64) -> zero intra-wave divergence
//     (was two dests/wave: wave ran max(deg_a,deg_b) iters, ~15-20% waste);
//     x->f16 convert fused into layer-1 GEMM (AF32 path, RNE pack in-reg).
//     R10 fixes R9's compile error (cvt_pkrtz returns __fp16 vec; use
//     __floats2half2_rn + bitcast instead).

typedef _Float16 h2 __attribute__((ext_vector_type(2)));
typedef _Float16 h8 __attribute__((ext_vector_type(8)));

__device__ inline uint pack_h2(float a, float b) {
    __half2 h = __floats2half2_rn(a, b);
    return *reinterpret_cast<uint*>(&h);
}

__device__ inline h2 pack_h2v(float a, float b) {
    uint u = pack_h2(a, b);
    return *reinterpret_cast<h2*>(&u);
}

__device__ inline float2 u_to_f2(uint u) {
    __half2 h = *reinterpret_cast<__half2*>(&u);
    return __half22float2(h);
}

__device__ inline float us_to_f(unsigned short u) {
    __half h = *reinterpret_cast<__half*>(&u);
    return __half2float(h);
}

// Zero counts[n] (int), vectorized int4.
__global__ __launch_bounds__(256) void zero_counts_kernel(int4* __restrict__ p, int n4) {
    int i = blockIdx.x * 256 + threadIdx.x;
    if (i < n4) p[i] = make_int4(0, 0, 0, 0);
}

__global__ void count_edges_kernel(const int* __restrict__ col, int* __restrict__ counts, int E) {
    int e = blockIdx.x * blockDim.x + threadIdx.x;
    if (e < E) atomicAdd(&counts[col[e]], 1);
}

// Stage 1: per-block (256 elements) sum of counts.
__global__ __launch_bounds__(256) void block_sum_kernel(const int* __restrict__ counts,
                                                        int* __restrict__ blocksum, int n) {
    int i = blockIdx.x * 256 + threadIdx.x;
    int v = (i < n) ? counts[i] : 0;
    #pragma unroll
    for (int d = 1; d < 64; d <<= 1) v += __shfl_xor(v, d);
    __shared__ int ws[4];
    if ((threadIdx.x & 63) == 0) ws[threadIdx.x >> 6] = v;
    __syncthreads();
    if (threadIdx.x == 0) blocksum[blockIdx.x] = ws[0] + ws[1] + ws[2] + ws[3];
}

// Stage 2: one block scans nb (<=256) block sums -> exclusive blockoff; offsets[n]=total.
__global__ __launch_bounds__(256) void scan_sums_kernel(const int* __restrict__ blocksum,
                                                        int* __restrict__ blockoff,
                                                        int* __restrict__ offsets, int nb, int n) {
    int tid = threadIdx.x;
    int lane = tid & 63, wid = tid >> 6;
    int orig = (tid < nb) ? blocksum[tid] : 0;
    int v = orig;
    #pragma unroll
    for (int d = 1; d < 64; d <<= 1) {
        int u = __shfl_up(v, d);
        if (lane >= d) v += u;
    }
    __shared__ int ws[4];
    if (lane == 63) ws[wid] = v;
    __syncthreads();
    int add = 0;
    for (int w = 0; w < wid; ++w) add += ws[w];
    v += add;                                  // inclusive
    if (tid < nb) blockoff[tid] = v - orig;    // exclusive
    if (tid == 255) offsets[n] = v;            // tail zeros -> total
}

// Stage 3: intra-chunk exclusive scan + blockoff -> offsets; zero cursor; fused dinv.
__global__ __launch_bounds__(256) void write_offsets_kernel(const int* __restrict__ counts,
                                                            const int* __restrict__ blockoff,
                                                            int* __restrict__ offsets,
                                                            int* __restrict__ cursor,
                                                            float* __restrict__ dinv, int n) {
    int tid = threadIdx.x;
    int i = blockIdx.x * 256 + tid;
    int lane = tid & 63, wid = tid >> 6;
    int c = (i < n) ? counts[i] : 0;
    int v = c;
    #pragma unroll
    for (int d = 1; d < 64; d <<= 1) {
        int u = __shfl_up(v, d);
        if (lane >= d) v += u;
    }
    __shared__ int ws[4];
    if (lane == 63) ws[wid] = v;
    __syncthreads();
    int add = 0;
    for (int w = 0; w < wid; ++w) add += ws[w];
    int incl = v + add;
    if (i < n) {
        offsets[i] = blockoff[blockIdx.x] + incl - c;
        cursor[i] = 0;
        dinv[i] = rsqrtf((float)(c + 1));      // +1 self loop
    }
}

// One 4B scattered store per edge: src index only.
__global__ void fill_csr_kernel(const int* __restrict__ row, const int* __restrict__ col,
                                const int* __restrict__ offsets, int* __restrict__ cursor,
                                int* __restrict__ srcs, int E) {
    int e = blockIdx.x * blockDim.x + threadIdx.x;
    if (e < E) {
        int c = col[e];
        int pos = offsets[c] + atomicAdd(&cursor[c], 1);
        srcs[pos] = row[e];
    }
}

// out16[n, DO] (f16) = dinv[row] * (A[n,128] @ W[128, DO]); fdot2, f32 acc.
// AF32: A is f32, converted in-register (RNE pack) -> fuses the x->f16 pass.
// W staged in LDS as k-pair-packed h2. Thread (rt, ct): R rows x 8 cols.
template <int DO, bool AF32>
__global__ __launch_bounds__(256, 2) void gemm16_kernel(const void* __restrict__ Ap,
                                                        const float* __restrict__ W,
                                                        const float* __restrict__ dinv,
                                                        __half* __restrict__ out, int n) {
    constexpr int K = 128;
    constexpr int COLTH = DO / 8;          // 16 (DO=128) or 8 (DO=64)
    constexpr int ROWTH = 256 / COLTH;     // 16 or 32
    constexpr int R = (DO == 128) ? 8 : 4; // rows per thread
    constexpr int BR = ROWTH * R;          // 128 rows per block
    constexpr int HALF = DO / 2;

    __shared__ alignas(16) h2 Wl[(K / 2) * DO];  // 32 KB (DO=128) / 16 KB (DO=64)

    int tid = threadIdx.x;
    for (int idx = tid; idx < (K / 2) * (DO / 4); idx += 256) {
        int k2 = idx / (DO / 4);
        int c4 = idx % (DO / 4);
        float4 w0 = ((const float4*)(W + (size_t)(2 * k2) * DO))[c4];
        float4 w1 = ((const float4*)(W + (size_t)(2 * k2 + 1) * DO))[c4];
        h2* dst = &Wl[k2 * DO + c4 * 4];
        h2 d0; d0.x = (_Float16)w0.x; d0.y = (_Float16)w1.x; dst[0] = d0;
        h2 d1; d1.x = (_Float16)w0.y; d1.y = (_Float16)w1.y; dst[1] = d1;
        h2 d2; d2.x = (_Float16)w0.z; d2.y = (_Float16)w1.z; dst[2] = d2;
        h2 d3; d3.x = (_Float16)w0.w; d3.y = (_Float16)w1.w; dst[3] = d3;
    }
    __syncthreads();

    int ct = tid % COLTH;
    int rt = tid / COLTH;
    int rb = blockIdx.x * BR + rt * R;

    int rowc[R];
    #pragma unroll
    for (int i = 0; i < R; ++i) {
        int row = rb + i;
        rowc[i] = (row < n) ? row : (n - 1);
    }

    float acc[R][8];
    #pragma unroll
    for (int i = 0; i < R; ++i)
        #pragma unroll
        for (int c = 0; c < 8; ++c) acc[i][c] = 0.f;

    #pragma unroll 2
    for (int k8 = 0; k8 < K / 8; ++k8) {
        h8 av[R];
        #pragma unroll
        for (int i = 0; i < R; ++i) {
            if (AF32) {
                const float4* A4 = (const float4*)Ap;
                float4 lo = A4[(size_t)rowc[i] * (K / 4) + k8 * 2];
                float4 hi = A4[(size_t)rowc[i] * (K / 4) + k8 * 2 + 1];
                h2 t0 = pack_h2v(lo.x, lo.y);
                h2 t1 = pack_h2v(lo.z, lo.w);
                h2 t2 = pack_h2v(hi.x, hi.y);
                h2 t3 = pack_h2v(hi.z, hi.w);
                h8 a;
                a[0] = t0.x; a[1] = t0.y; a[2] = t1.x; a[3] = t1.y;
                a[4] = t2.x; a[5] = t2.y; a[6] = t3.x; a[7] = t3.y;
                av[i] = a;
            } else {
                const h8* A8 = (const h8*)Ap;
                av[i] = A8[(size_t)rowc[i] * (K / 8) + k8];
            }
        }
        #pragma unroll
        for (int kk = 0; kk < 4; ++kk) {
            int k2 = k8 * 4 + kk;
            h2 w0[4], w1[4];
            *(uint4*)w0 = *(const uint4*)(&Wl[k2 * DO + ct * 4]);
            *(uint4*)w1 = *(const uint4*)(&Wl[k2 * DO + HALF + ct * 4]);
            #pragma unroll
            for (int i = 0; i < R; ++i) {
                h2 a; a.x = av[i][2 * kk]; a.y = av[i][2 * kk + 1];
                #pragma unroll
                for (int c = 0; c < 4; ++c) {
                    acc[i][c]     = __builtin_amdgcn_fdot2(a, w0[c], acc[i][c], false);
                    acc[i][4 + c] = __builtin_amdgcn_fdot2(a, w1[c], acc[i][4 + c], false);
                }
            }
        }
    }

    #pragma unroll
    for (int i = 0; i < R; ++i) {
        int row = rb + i;
        if (row < n) {
            float dv = dinv[row];
            uint2 q0 = make_uint2(pack_h2(acc[i][0] * dv, acc[i][1] * dv),
                                  pack_h2(acc[i][2] * dv, acc[i][3] * dv));
            uint2 q1 = make_uint2(pack_h2(acc[i][4] * dv, acc[i][5] * dv),
                                  pack_h2(acc[i][6] * dv, acc[i][7] * dv));
            *(uint2*)(out + (size_t)row * DO + ct * 4) = q0;
            *(uint2*)(out + (size_t)row * DO + HALF + ct * 4) = q1;
        }
    }
}

// out[d] = bias + dinv[d] * (hw_s[d] + sum_e hw_s[src(e)])   (f32 acc)
// ONE DEST PER WAVE. DO=128: lane covers 2 cols (4B h2); DO=64: 1 col (2B).
// Edge loop trip count is wave-uniform -> no divergence. Unroll x8 for MLP.
template <int DO, bool RELU, bool F16OUT>
__global__ __launch_bounds__(256) void agg_kernel(const __half* __restrict__ hw,
                                                  const int* __restrict__ offsets,
                                                  const int* __restrict__ srcs,
                                                  const float* __restrict__ dinv,
                                                  const float* __restrict__ bias,
                                                  void* __restrict__ outp, int n) {
    int wid = threadIdx.x >> 6;
    int lane = threadIdx.x & 63;
    int d = blockIdx.x * 4 + wid;
    if (d >= n) return;

    int beg = offsets[d];
    int end = offsets[d + 1];
    float di = dinv[d];

    if constexpr (DO == 128) {
        const uint* hwu = (const uint*)hw;     // h2 per lane
        size_t base = (size_t)d * 64 + lane;
        float2 acc = u_to_f2(hwu[base]);       // self term (pre-scaled)

        int e = beg;
        for (; e + 8 <= end; e += 8) {
            int s0 = srcs[e + 0], s1 = srcs[e + 1], s2 = srcs[e + 2], s3 = srcs[e + 3];
            int s4 = srcs[e + 4], s5 = srcs[e + 5], s6 = srcs[e + 6], s7 = srcs[e + 7];
            uint v0 = hwu[(size_t)s0 * 64 + lane];
            uint v1 = hwu[(size_t)s1 * 64 + lane];
            uint v2 = hwu[(size_t)s2 * 64 + lane];
            uint v3 = hwu[(size_t)s3 * 64 + lane];
            uint v4 = hwu[(size_t)s4 * 64 + lane];
            uint v5 = hwu[(size_t)s5 * 64 + lane];
            uint v6 = hwu[(size_t)s6 * 64 + lane];
            uint v7 = hwu[(size_t)s7 * 64 + lane];
            float2 f0 = u_to_f2(v0), f1 = u_to_f2(v1), f2 = u_to_f2(v2), f3 = u_to_f2(v3);
            float2 f4 = u_to_f2(v4), f5 = u_to_f2(v5), f6 = u_to_f2(v6), f7 = u_to_f2(v7);
            acc.x += f0.x; acc.y += f0.y; acc.x += f1.x; acc.y += f1.y;
            acc.x += f2.x; acc.y += f2.y; acc.x += f3.x; acc.y += f3.y;
            acc.x += f4.x; acc.y += f4.y; acc.x += f5.x; acc.y += f5.y;
            acc.x += f6.x; acc.y += f6.y; acc.x += f7.x; acc.y += f7.y;
        }
        for (; e + 4 <= end; e += 4) {
            int s0 = srcs[e + 0], s1 = srcs[e + 1], s2 = srcs[e + 2], s3 = srcs[e + 3];
            float2 f0 = u_to_f2(hwu[(size_t)s0 * 64 + lane]);
            float2 f1 = u_to_f2(hwu[(size_t)s1 * 64 + lane]);
            float2 f2 = u_to_f2(hwu[(size_t)s2 * 64 + lane]);
            float2 f3 = u_to_f2(hwu[(size_t)s3 * 64 + lane]);
            acc.x += f0.x; acc.y += f0.y; acc.x += f1.x; acc.y += f1.y;
            acc.x += f2.x; acc.y += f2.y; acc.x += f3.x; acc.y += f3.y;
        }
        for (; e < end; ++e) {
            float2 f = u_to_f2(hwu[(size_t)srcs[e] * 64 + lane]);
            acc.x += f.x; acc.y += f.y;
        }

        float2 b2 = ((const float2*)bias)[lane];
        acc.x = b2.x + di * acc.x;
        acc.y = b2.y + di * acc.y;
        if (RELU) { acc.x = fmaxf(acc.x, 0.f); acc.y = fmaxf(acc.y, 0.f); }
        if (F16OUT) {
            ((uint*)outp)[base] = pack_h2(acc.x, acc.y);
        } else {
            ((float2*)outp)[base] = acc;
        }
    } else {  // DO == 64: one col per lane (2B loads)
        const unsigned short* hwu = (const unsigned short*)hw;
        size_t base = (size_t)d * 64 + lane;
        float acc = us_to_f(hwu[base]);

        int e = beg;
        for (; e + 8 <= end; e += 8) {
            int s0 = srcs[e + 0], s1 = srcs[e + 1], s2 = srcs[e + 2], s3 = srcs[e + 3];
            int s4 = srcs[e + 4], s5 = srcs[e + 5], s6 = srcs[e + 6], s7 = srcs[e + 7];
            float f0 = us_to_f(hwu[(size_t)s0 * 64 + lane]);
            float f1 = us_to_f(hwu[(size_t)s1 * 64 + lane]);
            float f2 = us_to_f(hwu[(size_t)s2 * 64 + lane]);
            float f3 = us_to_f(hwu[(size_t)s3 * 64 + lane]);
            float f4 = us_to_f(hwu[(size_t)s4 * 64 + lane]);
            float f5 = us_to_f(hwu[(size_t)s5 * 64 + lane]);
            float f6 = us_to_f(hwu[(size_t)s6 * 64 + lane]);
            float f7 = us_to_f(hwu[(size_t)s7 * 64 + lane]);
            acc += f0 + f1 + f2 + f3 + f4 + f5 + f6 + f7;
        }
        for (; e < end; ++e) {
            acc += us_to_f(hwu[(size_t)srcs[e] * 64 + lane]);
        }

        acc = bias[lane] + di * acc;
        if (RELU) acc = fmaxf(acc, 0.f);
        ((float*)outp)[base] = acc;   // F16OUT unused for DO=64
    }
}

extern "C" void kernel_launch(void* const* d_in, const int* in_sizes, int n_in,
                              void* d_out, int out_size, void* d_ws, size_t ws_size,
                              hipStream_t stream) {
    const float* x  = (const float*)d_in[0];
    const float* W1 = (const float*)d_in[1];
    const float* b1 = (const float*)d_in[2];
    const float* W2 = (const float*)d_in[3];
    const float* b2 = (const float*)d_in[4];
    const float* W3 = (const float*)d_in[5];
    const float* b3 = (const float*)d_in[6];
    const int*   ei = (const int*)d_in[7];

    const int N = in_sizes[0] / 128;
    const int E = in_sizes[7] / 2;
    const int* rowi = ei;       // edge_index[0] = sources
    const int* coli = ei + E;   // edge_index[1] = targets

    float* out = (float*)d_out;

    // workspace carve-up (256B aligned)
    char* ws = (char*)d_ws;
    size_t off = 0;
    auto alloc = [&](size_t bytes) -> void* {
        void* p = ws + off;
        off = (off + bytes + 255) & ~(size_t)255;
        return p;
    };
    const int NB = (N + 255) / 256;
    float* dinv     = (float*)alloc((size_t)N * 4);
    int*   counts   = (int*)  alloc(((size_t)N + 4) * 4);  // int4-padded
    int*   offsets  = (int*)  alloc((size_t)(N + 1) * 4);
    int*   cursor   = (int*)  alloc((size_t)N * 4);
    int*   blocksum = (int*)  alloc((size_t)NB * 4);
    int*   blockoff = (int*)  alloc((size_t)NB * 4);
    int*   srcs     = (int*)  alloc((size_t)E * 4);
    __half* hw16    = (__half*)alloc((size_t)N * 128 * 2);
    __half* h16     = (__half*)alloc((size_t)N * 128 * 2);

    // ---- degree / norm / CSR ----
    const int n4 = (N + 3) / 4;
    zero_counts_kernel<<<(n4 + 255) / 256, 256, 0, stream>>>((int4*)counts, n4);
    count_edges_kernel<<<(E + 255) / 256, 256, 0, stream>>>(coli, counts, E);
    block_sum_kernel<<<NB, 256, 0, stream>>>(counts, blocksum, N);
    scan_sums_kernel<<<1, 256, 0, stream>>>(blocksum, blockoff, offsets, NB, N);
    write_offsets_kernel<<<NB, 256, 0, stream>>>(counts, blockoff, offsets, cursor, dinv, N);
    fill_csr_kernel<<<(E + 255) / 256, 256, 0, stream>>>(rowi, coli, offsets, cursor, srcs, E);

    // ---- layer 1 (x f32 read directly, converted in-reg) ----
    gemm16_kernel<128, true><<<(N + 127) / 128, 256, 0, stream>>>(x, W1, dinv, hw16, N);
    agg_kernel<128, true, true><<<(N + 3) / 4, 256, 0, stream>>>(hw16, offsets, srcs, dinv, b1, h16, N);

    // ---- layer 2 ----
    gemm16_kernel<128, false><<<(N + 127) / 128, 256, 0, stream>>>(h16, W2, dinv, hw16, N);
    agg_kernel<128, true, true><<<(N + 3) / 4, 256, 0, stream>>>(hw16, offsets, srcs, dinv, b2, h16, N);

    // ---- layer 3 (no relu), width 64, f32 out ----
    gemm16_kernel<64, false><<<(N + 127) / 128, 256, 0, stream>>>(h16, W3, dinv, hw16, N);
    agg_kernel<64, false, false><<<(N + 3) / 4, 256, 0, stream>>>(hw16, offsets, srcs, dinv, b3, out, N);
}

// Round 11
// 215.664 us; speedup vs baseline: 1.1263x; 1.1263x over previous
//
#include <hip/hip_runtime.h>
#include <hip/hip_bf16.h>
#include <hip/hip_fp16.h>

// GCN 3-layer: out = A_hat @ (A_hat @ relu(A_hat @ relu(X W1)+b1 ... ) )
// R2-R8: vectorized agg, W-LDS fdot2 GEMM, f16 activations, 4B edge records,
//        device-wide scan, norm factorized into GEMM epilogue.
// R10 post-mortem: AF32 fusion + one-dest-per-wave agg both regressed ->
//     reverted to R8 structure.
// R11: GEMM grid fix — BR=64 rows/block (782 blocks vs 391 on 256 CUs);
//     was ~1.5 blocks/CU -> 4 waves/CU -> latency exposed (VALUBusy 26%,
//     Occ 11%). Smaller blocks double residency + shrink imbalance tail.

typedef _Float16 h2 __attribute__((ext_vector_type(2)));
typedef _Float16 h8 __attribute__((ext_vector_type(8)));

__device__ inline float4 h4_to_f4(float2 raw) {
    __half2 lo = *reinterpret_cast<__half2*>(&raw.x);
    __half2 hi = *reinterpret_cast<__half2*>(&raw.y);
    float2 a = __half22float2(lo);
    float2 b = __half22float2(hi);
    return make_float4(a.x, a.y, b.x, b.y);
}

__device__ inline uint pack_h2(float a, float b) {
    __half2 h = __floats2half2_rn(a, b);
    return *reinterpret_cast<uint*>(&h);
}

// Zero counts[n] (int), vectorized int4.
__global__ __launch_bounds__(256) void zero_counts_kernel(int4* __restrict__ p, int n4) {
    int i = blockIdx.x * 256 + threadIdx.x;
    if (i < n4) p[i] = make_int4(0, 0, 0, 0);
}

// f32 -> f16, 4 elems/thread.
__global__ __launch_bounds__(256) void f32_to_f16_kernel(const float4* __restrict__ in,
                                                         uint2* __restrict__ out, int n4) {
    int i = blockIdx.x * 256 + threadIdx.x;
    if (i < n4) {
        float4 v = in[i];
        out[i] = make_uint2(pack_h2(v.x, v.y), pack_h2(v.z, v.w));
    }
}

__global__ void count_edges_kernel(const int* __restrict__ col, int* __restrict__ counts, int E) {
    int e = blockIdx.x * blockDim.x + threadIdx.x;
    if (e < E) atomicAdd(&counts[col[e]], 1);
}

// Stage 1: per-block (256 elements) sum of counts.
__global__ __launch_bounds__(256) void block_sum_kernel(const int* __restrict__ counts,
                                                        int* __restrict__ blocksum, int n) {
    int i = blockIdx.x * 256 + threadIdx.x;
    int v = (i < n) ? counts[i] : 0;
    #pragma unroll
    for (int d = 1; d < 64; d <<= 1) v += __shfl_xor(v, d);
    __shared__ int ws[4];
    if ((threadIdx.x & 63) == 0) ws[threadIdx.x >> 6] = v;
    __syncthreads();
    if (threadIdx.x == 0) blocksum[blockIdx.x] = ws[0] + ws[1] + ws[2] + ws[3];
}

// Stage 2: one block scans nb (<=256) block sums -> exclusive blockoff; offsets[n]=total.
__global__ __launch_bounds__(256) void scan_sums_kernel(const int* __restrict__ blocksum,
                                                        int* __restrict__ blockoff,
                                                        int* __restrict__ offsets, int nb, int n) {
    int tid = threadIdx.x;
    int lane = tid & 63, wid = tid >> 6;
    int orig = (tid < nb) ? blocksum[tid] : 0;
    int v = orig;
    #pragma unroll
    for (int d = 1; d < 64; d <<= 1) {
        int u = __shfl_up(v, d);
        if (lane >= d) v += u;
    }
    __shared__ int ws[4];
    if (lane == 63) ws[wid] = v;
    __syncthreads();
    int add = 0;
    for (int w = 0; w < wid; ++w) add += ws[w];
    v += add;                                  // inclusive
    if (tid < nb) blockoff[tid] = v - orig;    // exclusive
    if (tid == 255) offsets[n] = v;            // tail zeros -> total
}

// Stage 3: intra-chunk exclusive scan + blockoff -> offsets; zero cursor; fused dinv.
__global__ __launch_bounds__(256) void write_offsets_kernel(const int* __restrict__ counts,
                                                            const int* __restrict__ blockoff,
                                                            int* __restrict__ offsets,
                                                            int* __restrict__ cursor,
                                                            float* __restrict__ dinv, int n) {
    int tid = threadIdx.x;
    int i = blockIdx.x * 256 + tid;
    int lane = tid & 63, wid = tid >> 6;
    int c = (i < n) ? counts[i] : 0;
    int v = c;
    #pragma unroll
    for (int d = 1; d < 64; d <<= 1) {
        int u = __shfl_up(v, d);
        if (lane >= d) v += u;
    }
    __shared__ int ws[4];
    if (lane == 63) ws[wid] = v;
    __syncthreads();
    int add = 0;
    for (int w = 0; w < wid; ++w) add += ws[w];
    int incl = v + add;
    if (i < n) {
        offsets[i] = blockoff[blockIdx.x] + incl - c;
        cursor[i] = 0;
        dinv[i] = rsqrtf((float)(c + 1));      // +1 self loop
    }
}

// One 4B scattered store per edge: src index only.
__global__ void fill_csr_kernel(const int* __restrict__ row, const int* __restrict__ col,
                                const int* __restrict__ offsets, int* __restrict__ cursor,
                                int* __restrict__ srcs, int E) {
    int e = blockIdx.x * blockDim.x + threadIdx.x;
    if (e < E) {
        int c = col[e];
        int pos = offsets[c] + atomicAdd(&cursor[c], 1);
        srcs[pos] = row[e];
    }
}

// out16[n, DO] (f16) = dinv[row] * (A16[n,128] @ W[128, DO]); fdot2, f32 acc.
// W staged in LDS as k-pair-packed h2. R11: BR=64 rows/block -> 782 blocks.
template <int DO>
__global__ __launch_bounds__(256) void gemm16_kernel(const __half* __restrict__ A,
                                                     const float* __restrict__ W,
                                                     const float* __restrict__ dinv,
                                                     __half* __restrict__ out, int n) {
    constexpr int K = 128;
    constexpr int COLTH = DO / 8;          // 16 (DO=128) or 8 (DO=64)
    constexpr int ROWTH = 256 / COLTH;     // 16 or 32
    constexpr int R = 64 / ROWTH;          // 4 (DO=128) or 2 (DO=64)
    constexpr int BR = ROWTH * R;          // 64 rows per block
    constexpr int HALF = DO / 2;

    __shared__ alignas(16) h2 Wl[(K / 2) * DO];  // 32 KB (DO=128) / 16 KB (DO=64)

    int tid = threadIdx.x;
    for (int idx = tid; idx < (K / 2) * (DO / 4); idx += 256) {
        int k2 = idx / (DO / 4);
        int c4 = idx % (DO / 4);
        float4 w0 = ((const float4*)(W + (size_t)(2 * k2) * DO))[c4];
        float4 w1 = ((const float4*)(W + (size_t)(2 * k2 + 1) * DO))[c4];
        h2* dst = &Wl[k2 * DO + c4 * 4];
        h2 d0; d0.x = (_Float16)w0.x; d0.y = (_Float16)w1.x; dst[0] = d0;
        h2 d1; d1.x = (_Float16)w0.y; d1.y = (_Float16)w1.y; dst[1] = d1;
        h2 d2; d2.x = (_Float16)w0.z; d2.y = (_Float16)w1.z; dst[2] = d2;
        h2 d3; d3.x = (_Float16)w0.w; d3.y = (_Float16)w1.w; dst[3] = d3;
    }
    __syncthreads();

    int ct = tid % COLTH;
    int rt = tid / COLTH;
    int rb = blockIdx.x * BR + rt * R;

    int rowc[R];
    #pragma unroll
    for (int i = 0; i < R; ++i) {
        int row = rb + i;
        rowc[i] = (row < n) ? row : (n - 1);
    }

    float acc[R][8];
    #pragma unroll
    for (int i = 0; i < R; ++i)
        #pragma unroll
        for (int c = 0; c < 8; ++c) acc[i][c] = 0.f;

    #pragma unroll 2
    for (int k8 = 0; k8 < K / 8; ++k8) {
        h8 av[R];
        #pragma unroll
        for (int i = 0; i < R; ++i) {
            av[i] = ((const h8*)(A + (size_t)rowc[i] * K))[k8];
        }
        #pragma unroll
        for (int kk = 0; kk < 4; ++kk) {
            int k2 = k8 * 4 + kk;
            h2 w0[4], w1[4];
            *(uint4*)w0 = *(const uint4*)(&Wl[k2 * DO + ct * 4]);
            *(uint4*)w1 = *(const uint4*)(&Wl[k2 * DO + HALF + ct * 4]);
            #pragma unroll
            for (int i = 0; i < R; ++i) {
                h2 a; a.x = av[i][2 * kk]; a.y = av[i][2 * kk + 1];
                #pragma unroll
                for (int c = 0; c < 4; ++c) {
                    acc[i][c]     = __builtin_amdgcn_fdot2(a, w0[c], acc[i][c], false);
                    acc[i][4 + c] = __builtin_amdgcn_fdot2(a, w1[c], acc[i][4 + c], false);
                }
            }
        }
    }

    #pragma unroll
    for (int i = 0; i < R; ++i) {
        int row = rb + i;
        if (row < n) {
            float dv = dinv[row];
            uint2 q0 = make_uint2(pack_h2(acc[i][0] * dv, acc[i][1] * dv),
                                  pack_h2(acc[i][2] * dv, acc[i][3] * dv));
            uint2 q1 = make_uint2(pack_h2(acc[i][4] * dv, acc[i][5] * dv),
                                  pack_h2(acc[i][6] * dv, acc[i][7] * dv));
            *(uint2*)(out + (size_t)row * DO + ct * 4) = q0;
            *(uint2*)(out + (size_t)row * DO + HALF + ct * 4) = q1;
        }
    }
}

// out[d] = bias + dinv[d] * (hw_s[d] + sum_e hw_s[src(e)])   (f32 acc)
// hw_s rows pre-scaled by dinv[row]. TPD = DO/4 lanes/dest, 8B f16 gathers,
// unroll x8, per-edge work = pure adds. (R8 structure, measured-good.)
template <int DO, bool RELU, bool F16OUT>
__global__ __launch_bounds__(256) void agg_kernel(const __half* __restrict__ hw,
                                                  const int* __restrict__ offsets,
                                                  const int* __restrict__ srcs,
                                                  const float* __restrict__ dinv,
                                                  const float* __restrict__ bias,
                                                  void* __restrict__ outp, int n) {
    constexpr int TPD = DO / 4;            // lanes per dest
    constexpr int DPB = 256 / TPD;         // dests per block
    int d = blockIdx.x * DPB + threadIdx.x / TPD;
    int j = threadIdx.x % TPD;             // 4-col chunk index
    if (d >= n) return;

    const float2* hw2 = (const float2*)hw; // 4 halves per unit
    int beg = offsets[d];
    int end = offsets[d + 1];

    float4 acc = h4_to_f4(hw2[(size_t)d * TPD + j]);   // self term (pre-scaled)

    int e = beg;
    for (; e + 8 <= end; e += 8) {
        int s0 = srcs[e + 0], s1 = srcs[e + 1], s2 = srcs[e + 2], s3 = srcs[e + 3];
        int s4 = srcs[e + 4], s5 = srcs[e + 5], s6 = srcs[e + 6], s7 = srcs[e + 7];
        float4 v0 = h4_to_f4(hw2[(size_t)s0 * TPD + j]);
        float4 v1 = h4_to_f4(hw2[(size_t)s1 * TPD + j]);
        float4 v2 = h4_to_f4(hw2[(size_t)s2 * TPD + j]);
        float4 v3 = h4_to_f4(hw2[(size_t)s3 * TPD + j]);
        float4 v4 = h4_to_f4(hw2[(size_t)s4 * TPD + j]);
        float4 v5 = h4_to_f4(hw2[(size_t)s5 * TPD + j]);
        float4 v6 = h4_to_f4(hw2[(size_t)s6 * TPD + j]);
        float4 v7 = h4_to_f4(hw2[(size_t)s7 * TPD + j]);
        acc.x += v0.x; acc.y += v0.y; acc.z += v0.z; acc.w += v0.w;
        acc.x += v1.x; acc.y += v1.y; acc.z += v1.z; acc.w += v1.w;
        acc.x += v2.x; acc.y += v2.y; acc.z += v2.z; acc.w += v2.w;
        acc.x += v3.x; acc.y += v3.y; acc.z += v3.z; acc.w += v3.w;
        acc.x += v4.x; acc.y += v4.y; acc.z += v4.z; acc.w += v4.w;
        acc.x += v5.x; acc.y += v5.y; acc.z += v5.z; acc.w += v5.w;
        acc.x += v6.x; acc.y += v6.y; acc.z += v6.z; acc.w += v6.w;
        acc.x += v7.x; acc.y += v7.y; acc.z += v7.z; acc.w += v7.w;
    }
    for (; e + 4 <= end; e += 4) {
        int s0 = srcs[e + 0], s1 = srcs[e + 1], s2 = srcs[e + 2], s3 = srcs[e + 3];
        float4 v0 = h4_to_f4(hw2[(size_t)s0 * TPD + j]);
        float4 v1 = h4_to_f4(hw2[(size_t)s1 * TPD + j]);
        float4 v2 = h4_to_f4(hw2[(size_t)s2 * TPD + j]);
        float4 v3 = h4_to_f4(hw2[(size_t)s3 * TPD + j]);
        acc.x += v0.x; acc.y += v0.y; acc.z += v0.z; acc.w += v0.w;
        acc.x += v1.x; acc.y += v1.y; acc.z += v1.z; acc.w += v1.w;
        acc.x += v2.x; acc.y += v2.y; acc.z += v2.z; acc.w += v2.w;
        acc.x += v3.x; acc.y += v3.y; acc.z += v3.z; acc.w += v3.w;
    }
    for (; e < end; ++e) {
        float4 v = h4_to_f4(hw2[(size_t)srcs[e] * TPD + j]);
        acc.x += v.x; acc.y += v.y; acc.z += v.z; acc.w += v.w;
    }

    float di = dinv[d];
    float4 b4 = ((const float4*)bias)[j];
    acc.x = b4.x + di * acc.x;
    acc.y = b4.y + di * acc.y;
    acc.z = b4.z + di * acc.z;
    acc.w = b4.w + di * acc.w;

    if (RELU) {
        acc.x = fmaxf(acc.x, 0.f); acc.y = fmaxf(acc.y, 0.f);
        acc.z = fmaxf(acc.z, 0.f); acc.w = fmaxf(acc.w, 0.f);
    }
    if (F16OUT) {
        uint2 q = make_uint2(pack_h2(acc.x, acc.y), pack_h2(acc.z, acc.w));
        ((uint2*)outp)[(size_t)d * TPD + j] = q;
    } else {
        ((float4*)outp)[(size_t)d * TPD + j] = acc;
    }
}

extern "C" void kernel_launch(void* const* d_in, const int* in_sizes, int n_in,
                              void* d_out, int out_size, void* d_ws, size_t ws_size,
                              hipStream_t stream) {
    const float* x  = (const float*)d_in[0];
    const float* W1 = (const float*)d_in[1];
    const float* b1 = (const float*)d_in[2];
    const float* W2 = (const float*)d_in[3];
    const float* b2 = (const float*)d_in[4];
    const float* W3 = (const float*)d_in[5];
    const float* b3 = (const float*)d_in[6];
    const int*   ei = (const int*)d_in[7];

    const int N = in_sizes[0] / 128;
    const int E = in_sizes[7] / 2;
    const int* rowi = ei;       // edge_index[0] = sources
    const int* coli = ei + E;   // edge_index[1] = targets

    float* out = (float*)d_out;

    // workspace carve-up (256B aligned)
    char* ws = (char*)d_ws;
    size_t off = 0;
    auto alloc = [&](size_t bytes) -> void* {
        void* p = ws + off;
        off = (off + bytes + 255) & ~(size_t)255;
        return p;
    };
    const int NB = (N + 255) / 256;
    float* dinv     = (float*)alloc((size_t)N * 4);
    int*   counts   = (int*)  alloc(((size_t)N + 4) * 4);  // int4-padded
    int*   offsets  = (int*)  alloc((size_t)(N + 1) * 4);
    int*   cursor   = (int*)  alloc((size_t)N * 4);
    int*   blocksum = (int*)  alloc((size_t)NB * 4);
    int*   blockoff = (int*)  alloc((size_t)NB * 4);
    int*   srcs     = (int*)  alloc((size_t)E * 4);
    __half* x16     = (__half*)alloc((size_t)N * 128 * 2);
    __half* hw16    = (__half*)alloc((size_t)N * 128 * 2);
    __half* h16     = (__half*)alloc((size_t)N * 128 * 2);

    // ---- degree / norm / CSR  +  x -> f16 ----
    const int n4 = (N + 3) / 4;
    zero_counts_kernel<<<(n4 + 255) / 256, 256, 0, stream>>>((int4*)counts, n4);
    count_edges_kernel<<<(E + 255) / 256, 256, 0, stream>>>(coli, counts, E);
    block_sum_kernel<<<NB, 256, 0, stream>>>(counts, blocksum, N);
    scan_sums_kernel<<<1, 256, 0, stream>>>(blocksum, blockoff, offsets, NB, N);
    write_offsets_kernel<<<NB, 256, 0, stream>>>(counts, blockoff, offsets, cursor, dinv, N);
    fill_csr_kernel<<<(E + 255) / 256, 256, 0, stream>>>(rowi, coli, offsets, cursor, srcs, E);
    const int xc4 = N * 128 / 4;
    f32_to_f16_kernel<<<(xc4 + 255) / 256, 256, 0, stream>>>((const float4*)x, (uint2*)x16, xc4);

    // ---- layer 1 ----
    gemm16_kernel<128><<<(N + 63) / 64, 256, 0, stream>>>(x16, W1, dinv, hw16, N);
    agg_kernel<128, true, true><<<(N + 7) / 8, 256, 0, stream>>>(hw16, offsets, srcs, dinv, b1, h16, N);

    // ---- layer 2 ----
    gemm16_kernel<128><<<(N + 63) / 64, 256, 0, stream>>>(h16, W2, dinv, hw16, N);
    agg_kernel<128, true, true><<<(N + 7) / 8, 256, 0, stream>>>(hw16, offsets, srcs, dinv, b2, h16, N);

    // ---- layer 3 (no relu), width 64, f32 out ----
    gemm16_kernel<64><<<(N + 63) / 64, 256, 0, stream>>>(h16, W3, dinv, hw16, N);
    agg_kernel<64, false, false><<<(N + 15) / 16, 256, 0, stream>>>(hw16, offsets, srcs, dinv, b3, out, N);
}

// Round 12
// 211.023 us; speedup vs baseline: 1.1510x; 1.0220x over previous
//
#include <hip/hip_runtime.h>
#include <hip/hip_bf16.h>
#include <hip/hip_fp16.h>

// GCN 3-layer: out = A_hat @ (A_hat @ relu(A_hat @ relu(X W1)+b1 ... ) )
// R2-R11: vectorized agg, W-LDS fdot2 GEMM (BR=64 grid fix), f16 activations,
//         4B edge records, norm factorized into GEMM epilogue.
// R12: prelude fusion — {zero,convert,slot-init} one kernel; {bsum,ssum,woff}
//      one single-launch lookback scan (publish-then-poll, 196 blocks all
//      co-resident). 13 -> 10 dispatches. agg srcs loads software-pipelined
//      (next batch's indices load under current batch's gathers).

typedef _Float16 h2 __attribute__((ext_vector_type(2)));
typedef _Float16 h8 __attribute__((ext_vector_type(8)));

__device__ inline float4 h4_to_f4(float2 raw) {
    __half2 lo = *reinterpret_cast<__half2*>(&raw.x);
    __half2 hi = *reinterpret_cast<__half2*>(&raw.y);
    float2 a = __half22float2(lo);
    float2 b = __half22float2(hi);
    return make_float4(a.x, a.y, b.x, b.y);
}

__device__ inline uint pack_h2(float a, float b) {
    __half2 h = __floats2half2_rn(a, b);
    return *reinterpret_cast<uint*>(&h);
}

// Fused prelude: zero counts, init scan aggregate slots to -1, convert x->f16.
__global__ __launch_bounds__(256) void prelude_init_kernel(const float4* __restrict__ x,
                                                           uint2* __restrict__ x16,
                                                           int4* __restrict__ counts4, int n4,
                                                           int* __restrict__ aggslot, int nb,
                                                           int xc4) {
    int i = blockIdx.x * 256 + threadIdx.x;
    if (i < n4) counts4[i] = make_int4(0, 0, 0, 0);
    if (i < nb) aggslot[i] = -1;
    if (i < xc4) {
        float4 v = x[i];
        x16[i] = make_uint2(pack_h2(v.x, v.y), pack_h2(v.z, v.w));
    }
}

__global__ void count_edges_kernel(const int* __restrict__ col, int* __restrict__ counts, int E) {
    int e = blockIdx.x * blockDim.x + threadIdx.x;
    if (e < E) atomicAdd(&counts[col[e]], 1);
}

// Single-launch scan (lookback): each block publishes its aggregate first,
// then polls all predecessors' aggregates (publish-before-poll: no circular
// wait; 196 blocks << residency capacity so all dispatch). Produces offsets,
// zeroed cursor, fused dinv, offsets[n]=total.
__global__ __launch_bounds__(256) void scan_fused_kernel(const int* __restrict__ counts,
                                                         int* __restrict__ aggslot,
                                                         int* __restrict__ offsets,
                                                         int* __restrict__ cursor,
                                                         float* __restrict__ dinv, int n) {
    int b = blockIdx.x;
    int tid = threadIdx.x;
    int lane = tid & 63, wid = tid >> 6;
    int i = b * 256 + tid;
    int c = (i < n) ? counts[i] : 0;

    // intra-block inclusive scan
    int s = c;
    #pragma unroll
    for (int d = 1; d < 64; d <<= 1) {
        int u = __shfl_up(s, d);
        if (lane >= d) s += u;
    }
    __shared__ int ws[4];
    if (lane == 63) ws[wid] = s;
    __syncthreads();
    int add = 0;
    for (int w = 0; w < wid; ++w) add += ws[w];
    int incl = s + add;
    int blocktotal = ws[0] + ws[1] + ws[2] + ws[3];
    __syncthreads();   // everyone done reading ws before reuse

    // publish aggregate (device-scope atomic: cross-XCD coherent)
    if (tid == 0) atomicExch(&aggslot[b], blocktotal);

    // poll predecessors' aggregates, sum
    int pre = 0;
    for (int t = tid; t < b; t += 256) {
        int a;
        do { a = atomicAdd(&aggslot[t], 0); } while (a < 0);
        pre += a;
    }
    #pragma unroll
    for (int d = 1; d < 64; d <<= 1) pre += __shfl_xor(pre, d);
    if (lane == 0) ws[wid] = pre;
    __syncthreads();
    int blockoff = ws[0] + ws[1] + ws[2] + ws[3];

    if (i < n) {
        offsets[i] = blockoff + incl - c;
        cursor[i] = 0;
        dinv[i] = rsqrtf((float)(c + 1));      // +1 self loop
    }
    if (i == n - 1) offsets[n] = blockoff + incl;
}

// One 4B scattered store per edge: src index only.
__global__ void fill_csr_kernel(const int* __restrict__ row, const int* __restrict__ col,
                                const int* __restrict__ offsets, int* __restrict__ cursor,
                                int* __restrict__ srcs, int E) {
    int e = blockIdx.x * blockDim.x + threadIdx.x;
    if (e < E) {
        int c = col[e];
        int pos = offsets[c] + atomicAdd(&cursor[c], 1);
        srcs[pos] = row[e];
    }
}

// out16[n, DO] (f16) = dinv[row] * (A16[n,128] @ W[128, DO]); fdot2, f32 acc.
// W staged in LDS as k-pair-packed h2. BR=64 rows/block (782 blocks, R11).
template <int DO>
__global__ __launch_bounds__(256) void gemm16_kernel(const __half* __restrict__ A,
                                                     const float* __restrict__ W,
                                                     const float* __restrict__ dinv,
                                                     __half* __restrict__ out, int n) {
    constexpr int K = 128;
    constexpr int COLTH = DO / 8;          // 16 (DO=128) or 8 (DO=64)
    constexpr int ROWTH = 256 / COLTH;     // 16 or 32
    constexpr int R = 64 / ROWTH;          // 4 (DO=128) or 2 (DO=64)
    constexpr int BR = ROWTH * R;          // 64 rows per block
    constexpr int HALF = DO / 2;

    __shared__ alignas(16) h2 Wl[(K / 2) * DO];  // 32 KB (DO=128) / 16 KB (DO=64)

    int tid = threadIdx.x;
    for (int idx = tid; idx < (K / 2) * (DO / 4); idx += 256) {
        int k2 = idx / (DO / 4);
        int c4 = idx % (DO / 4);
        float4 w0 = ((const float4*)(W + (size_t)(2 * k2) * DO))[c4];
        float4 w1 = ((const float4*)(W + (size_t)(2 * k2 + 1) * DO))[c4];
        h2* dst = &Wl[k2 * DO + c4 * 4];
        h2 d0; d0.x = (_Float16)w0.x; d0.y = (_Float16)w1.x; dst[0] = d0;
        h2 d1; d1.x = (_Float16)w0.y; d1.y = (_Float16)w1.y; dst[1] = d1;
        h2 d2; d2.x = (_Float16)w0.z; d2.y = (_Float16)w1.z; dst[2] = d2;
        h2 d3; d3.x = (_Float16)w0.w; d3.y = (_Float16)w1.w; dst[3] = d3;
    }
    __syncthreads();

    int ct = tid % COLTH;
    int rt = tid / COLTH;
    int rb = blockIdx.x * BR + rt * R;

    int rowc[R];
    #pragma unroll
    for (int i = 0; i < R; ++i) {
        int row = rb + i;
        rowc[i] = (row < n) ? row : (n - 1);
    }

    float acc[R][8];
    #pragma unroll
    for (int i = 0; i < R; ++i)
        #pragma unroll
        for (int c = 0; c < 8; ++c) acc[i][c] = 0.f;

    #pragma unroll 2
    for (int k8 = 0; k8 < K / 8; ++k8) {
        h8 av[R];
        #pragma unroll
        for (int i = 0; i < R; ++i) {
            av[i] = ((const h8*)(A + (size_t)rowc[i] * K))[k8];
        }
        #pragma unroll
        for (int kk = 0; kk < 4; ++kk) {
            int k2 = k8 * 4 + kk;
            h2 w0[4], w1[4];
            *(uint4*)w0 = *(const uint4*)(&Wl[k2 * DO + ct * 4]);
            *(uint4*)w1 = *(const uint4*)(&Wl[k2 * DO + HALF + ct * 4]);
            #pragma unroll
            for (int i = 0; i < R; ++i) {
                h2 a; a.x = av[i][2 * kk]; a.y = av[i][2 * kk + 1];
                #pragma unroll
                for (int c = 0; c < 4; ++c) {
                    acc[i][c]     = __builtin_amdgcn_fdot2(a, w0[c], acc[i][c], false);
                    acc[i][4 + c] = __builtin_amdgcn_fdot2(a, w1[c], acc[i][4 + c], false);
                }
            }
        }
    }

    #pragma unroll
    for (int i = 0; i < R; ++i) {
        int row = rb + i;
        if (row < n) {
            float dv = dinv[row];
            uint2 q0 = make_uint2(pack_h2(acc[i][0] * dv, acc[i][1] * dv),
                                  pack_h2(acc[i][2] * dv, acc[i][3] * dv));
            uint2 q1 = make_uint2(pack_h2(acc[i][4] * dv, acc[i][5] * dv),
                                  pack_h2(acc[i][6] * dv, acc[i][7] * dv));
            *(uint2*)(out + (size_t)row * DO + ct * 4) = q0;
            *(uint2*)(out + (size_t)row * DO + HALF + ct * 4) = q1;
        }
    }
}

// out[d] = bias + dinv[d] * (hw_s[d] + sum_e hw_s[src(e)])   (f32 acc)
// TPD = DO/4 lanes/dest, 8B f16 gathers. R12: srcs loads software-pipelined —
// next batch's 8 indices load while current batch's gathers are in flight.
template <int DO, bool RELU, bool F16OUT>
__global__ __launch_bounds__(256) void agg_kernel(const __half* __restrict__ hw,
                                                  const int* __restrict__ offsets,
                                                  const int* __restrict__ srcs,
                                                  const float* __restrict__ dinv,
                                                  const float* __restrict__ bias,
                                                  void* __restrict__ outp, int n) {
    constexpr int TPD = DO / 4;            // lanes per dest
    constexpr int DPB = 256 / TPD;         // dests per block
    int d = blockIdx.x * DPB + threadIdx.x / TPD;
    int j = threadIdx.x % TPD;             // 4-col chunk index
    if (d >= n) return;

    const float2* hw2 = (const float2*)hw; // 4 halves per unit
    int beg = offsets[d];
    int end = offsets[d + 1];

    float4 acc = h4_to_f4(hw2[(size_t)d * TPD + j]);   // self term (pre-scaled)

    int e = beg;
    if (e + 8 <= end) {
        int cs[8];
        #pragma unroll
        for (int k = 0; k < 8; ++k) cs[k] = srcs[e + k];
        while (true) {
            float2 g[8];
            #pragma unroll
            for (int k = 0; k < 8; ++k) g[k] = hw2[(size_t)cs[k] * TPD + j];
            e += 8;
            bool more = (e + 8 <= end);
            int nx[8];
            if (more) {
                #pragma unroll
                for (int k = 0; k < 8; ++k) nx[k] = srcs[e + k];
            }
            #pragma unroll
            for (int k = 0; k < 8; ++k) {
                float4 f = h4_to_f4(g[k]);
                acc.x += f.x; acc.y += f.y; acc.z += f.z; acc.w += f.w;
            }
            if (!more) break;
            #pragma unroll
            for (int k = 0; k < 8; ++k) cs[k] = nx[k];
        }
    }
    for (; e + 4 <= end; e += 4) {
        int s0 = srcs[e + 0], s1 = srcs[e + 1], s2 = srcs[e + 2], s3 = srcs[e + 3];
        float4 v0 = h4_to_f4(hw2[(size_t)s0 * TPD + j]);
        float4 v1 = h4_to_f4(hw2[(size_t)s1 * TPD + j]);
        float4 v2 = h4_to_f4(hw2[(size_t)s2 * TPD + j]);
        float4 v3 = h4_to_f4(hw2[(size_t)s3 * TPD + j]);
        acc.x += v0.x; acc.y += v0.y; acc.z += v0.z; acc.w += v0.w;
        acc.x += v1.x; acc.y += v1.y; acc.z += v1.z; acc.w += v1.w;
        acc.x += v2.x; acc.y += v2.y; acc.z += v2.z; acc.w += v2.w;
        acc.x += v3.x; acc.y += v3.y; acc.z += v3.z; acc.w += v3.w;
    }
    for (; e < end; ++e) {
        float4 v = h4_to_f4(hw2[(size_t)srcs[e] * TPD + j]);
        acc.x += v.x; acc.y += v.y; acc.z += v.z; acc.w += v.w;
    }

    float di = dinv[d];
    float4 b4 = ((const float4*)bias)[j];
    acc.x = b4.x + di * acc.x;
    acc.y = b4.y + di * acc.y;
    acc.z = b4.z + di * acc.z;
    acc.w = b4.w + di * acc.w;

    if (RELU) {
        acc.x = fmaxf(acc.x, 0.f); acc.y = fmaxf(acc.y, 0.f);
        acc.z = fmaxf(acc.z, 0.f); acc.w = fmaxf(acc.w, 0.f);
    }
    if (F16OUT) {
        uint2 q = make_uint2(pack_h2(acc.x, acc.y), pack_h2(acc.z, acc.w));
        ((uint2*)outp)[(size_t)d * TPD + j] = q;
    } else {
        ((float4*)outp)[(size_t)d * TPD + j] = acc;
    }
}

extern "C" void kernel_launch(void* const* d_in, const int* in_sizes, int n_in,
                              void* d_out, int out_size, void* d_ws, size_t ws_size,
                              hipStream_t stream) {
    const float* x  = (const float*)d_in[0];
    const float* W1 = (const float*)d_in[1];
    const float* b1 = (const float*)d_in[2];
    const float* W2 = (const float*)d_in[3];
    const float* b2 = (const float*)d_in[4];
    const float* W3 = (const float*)d_in[5];
    const float* b3 = (const float*)d_in[6];
    const int*   ei = (const int*)d_in[7];

    const int N = in_sizes[0] / 128;
    const int E = in_sizes[7] / 2;
    const int* rowi = ei;       // edge_index[0] = sources
    const int* coli = ei + E;   // edge_index[1] = targets

    float* out = (float*)d_out;

    // workspace carve-up (256B aligned)
    char* ws = (char*)d_ws;
    size_t off = 0;
    auto alloc = [&](size_t bytes) -> void* {
        void* p = ws + off;
        off = (off + bytes + 255) & ~(size_t)255;
        return p;
    };
    const int NB = (N + 255) / 256;        // scan blocks (196 for N=50000)
    float* dinv     = (float*)alloc((size_t)N * 4);
    int*   counts   = (int*)  alloc(((size_t)N + 4) * 4);  // int4-padded
    int*   offsets  = (int*)  alloc((size_t)(N + 1) * 4);
    int*   cursor   = (int*)  alloc((size_t)N * 4);
    int*   aggslot  = (int*)  alloc((size_t)NB * 4);
    int*   srcs     = (int*)  alloc((size_t)E * 4);
    __half* x16     = (__half*)alloc((size_t)N * 128 * 2);
    __half* hw16    = (__half*)alloc((size_t)N * 128 * 2);
    __half* h16     = (__half*)alloc((size_t)N * 128 * 2);

    // ---- fused prelude: zero counts + init slots + x->f16 ----
    const int n4 = (N + 3) / 4;
    const int xc4 = N * 128 / 4;
    prelude_init_kernel<<<(xc4 + 255) / 256, 256, 0, stream>>>(
        (const float4*)x, (uint2*)x16, (int4*)counts, n4, aggslot, NB, xc4);
    count_edges_kernel<<<(E + 255) / 256, 256, 0, stream>>>(coli, counts, E);
    scan_fused_kernel<<<NB, 256, 0, stream>>>(counts, aggslot, offsets, cursor, dinv, N);
    fill_csr_kernel<<<(E + 255) / 256, 256, 0, stream>>>(rowi, coli, offsets, cursor, srcs, E);

    // ---- layer 1 ----
    gemm16_kernel<128><<<(N + 63) / 64, 256, 0, stream>>>(x16, W1, dinv, hw16, N);
    agg_kernel<128, true, true><<<(N + 7) / 8, 256, 0, stream>>>(hw16, offsets, srcs, dinv, b1, h16, N);

    // ---- layer 2 ----
    gemm16_kernel<128><<<(N + 63) / 64, 256, 0, stream>>>(h16, W2, dinv, hw16, N);
    agg_kernel<128, true, true><<<(N + 7) / 8, 256, 0, stream>>>(hw16, offsets, srcs, dinv, b2, h16, N);

    // ---- layer 3 (no relu), width 64, f32 out ----
    gemm16_kernel<64><<<(N + 63) / 64, 256, 0, stream>>>(h16, W3, dinv, hw16, N);
    agg_kernel<64, false, false><<<(N + 15) / 16, 256, 0, stream>>>(hw16, offsets, srcs, dinv, b3, out, N);
}

// Round 13
// 206.755 us; speedup vs baseline: 1.1748x; 1.0206x over previous
//
#include <hip/hip_runtime.h>
#include <hip/hip_bf16.h>
#include <hip/hip_fp16.h>

// GCN 3-layer: out = A_hat @ (A_hat @ relu(A_hat @ relu(X W1)+b1 ... ) )
// R2-R12: vectorized agg, W-LDS fdot2 GEMM (BR=64), f16 activations, 4B edge
//         records, norm factorized into GEMM epilogue, fused prelude +
//         single-launch lookback scan, pipelined agg srcs loads.
// R13: fill_csr + layer-1 GEMM fused via block-range split (independent after
//      scan/prelude; disjoint resources: random-scatter vs VALU/LDS). gemm1's
//      ~9us hides under fill's scatter. 10 -> 9 dispatches.

typedef _Float16 h2 __attribute__((ext_vector_type(2)));
typedef _Float16 h8 __attribute__((ext_vector_type(8)));

__device__ inline float4 h4_to_f4(float2 raw) {
    __half2 lo = *reinterpret_cast<__half2*>(&raw.x);
    __half2 hi = *reinterpret_cast<__half2*>(&raw.y);
    float2 a = __half22float2(lo);
    float2 b = __half22float2(hi);
    return make_float4(a.x, a.y, b.x, b.y);
}

__device__ inline uint pack_h2(float a, float b) {
    __half2 h = __floats2half2_rn(a, b);
    return *reinterpret_cast<uint*>(&h);
}

// Fused prelude: zero counts, init scan aggregate slots to -1, convert x->f16.
__global__ __launch_bounds__(256) void prelude_init_kernel(const float4* __restrict__ x,
                                                           uint2* __restrict__ x16,
                                                           int4* __restrict__ counts4, int n4,
                                                           int* __restrict__ aggslot, int nb,
                                                           int xc4) {
    int i = blockIdx.x * 256 + threadIdx.x;
    if (i < n4) counts4[i] = make_int4(0, 0, 0, 0);
    if (i < nb) aggslot[i] = -1;
    if (i < xc4) {
        float4 v = x[i];
        x16[i] = make_uint2(pack_h2(v.x, v.y), pack_h2(v.z, v.w));
    }
}

__global__ void count_edges_kernel(const int* __restrict__ col, int* __restrict__ counts, int E) {
    int e = blockIdx.x * blockDim.x + threadIdx.x;
    if (e < E) atomicAdd(&counts[col[e]], 1);
}

// Single-launch scan (lookback): publish aggregate, then poll predecessors.
__global__ __launch_bounds__(256) void scan_fused_kernel(const int* __restrict__ counts,
                                                         int* __restrict__ aggslot,
                                                         int* __restrict__ offsets,
                                                         int* __restrict__ cursor,
                                                         float* __restrict__ dinv, int n) {
    int b = blockIdx.x;
    int tid = threadIdx.x;
    int lane = tid & 63, wid = tid >> 6;
    int i = b * 256 + tid;
    int c = (i < n) ? counts[i] : 0;

    int s = c;
    #pragma unroll
    for (int d = 1; d < 64; d <<= 1) {
        int u = __shfl_up(s, d);
        if (lane >= d) s += u;
    }
    __shared__ int ws[4];
    if (lane == 63) ws[wid] = s;
    __syncthreads();
    int add = 0;
    for (int w = 0; w < wid; ++w) add += ws[w];
    int incl = s + add;
    int blocktotal = ws[0] + ws[1] + ws[2] + ws[3];
    __syncthreads();

    if (tid == 0) atomicExch(&aggslot[b], blocktotal);

    int pre = 0;
    for (int t = tid; t < b; t += 256) {
        int a;
        do { a = atomicAdd(&aggslot[t], 0); } while (a < 0);
        pre += a;
    }
    #pragma unroll
    for (int d = 1; d < 64; d <<= 1) pre += __shfl_xor(pre, d);
    if (lane == 0) ws[wid] = pre;
    __syncthreads();
    int blockoff = ws[0] + ws[1] + ws[2] + ws[3];

    if (i < n) {
        offsets[i] = blockoff + incl - c;
        cursor[i] = 0;
        dinv[i] = rsqrtf((float)(c + 1));      // +1 self loop
    }
    if (i == n - 1) offsets[n] = blockoff + incl;
}

// GEMM tile body: 64 rows x DO cols, fdot2, f32 acc, dinv-scaled f16 store.
// W staged in LDS as k-pair-packed h2 by THIS block's 256 threads.
template <int DO>
__device__ __forceinline__ void gemm_tile_body(int tileb,
                                               const __half* __restrict__ A,
                                               const float* __restrict__ W,
                                               const float* __restrict__ dinv,
                                               __half* __restrict__ out, int n,
                                               h2* Wl) {
    constexpr int K = 128;
    constexpr int COLTH = DO / 8;          // 16 (DO=128) or 8 (DO=64)
    constexpr int ROWTH = 256 / COLTH;     // 16 or 32
    constexpr int R = 64 / ROWTH;          // 4 (DO=128) or 2 (DO=64)
    constexpr int BR = ROWTH * R;          // 64 rows per block
    constexpr int HALF = DO / 2;

    int tid = threadIdx.x;
    for (int idx = tid; idx < (K / 2) * (DO / 4); idx += 256) {
        int k2 = idx / (DO / 4);
        int c4 = idx % (DO / 4);
        float4 w0 = ((const float4*)(W + (size_t)(2 * k2) * DO))[c4];
        float4 w1 = ((const float4*)(W + (size_t)(2 * k2 + 1) * DO))[c4];
        h2* dst = &Wl[k2 * DO + c4 * 4];
        h2 d0; d0.x = (_Float16)w0.x; d0.y = (_Float16)w1.x; dst[0] = d0;
        h2 d1; d1.x = (_Float16)w0.y; d1.y = (_Float16)w1.y; dst[1] = d1;
        h2 d2; d2.x = (_Float16)w0.z; d2.y = (_Float16)w1.z; dst[2] = d2;
        h2 d3; d3.x = (_Float16)w0.w; d3.y = (_Float16)w1.w; dst[3] = d3;
    }
    __syncthreads();

    int ct = tid % COLTH;
    int rt = tid / COLTH;
    int rb = tileb * BR + rt * R;

    int rowc[R];
    #pragma unroll
    for (int i = 0; i < R; ++i) {
        int row = rb + i;
        rowc[i] = (row < n) ? row : (n - 1);
    }

    float acc[R][8];
    #pragma unroll
    for (int i = 0; i < R; ++i)
        #pragma unroll
        for (int c = 0; c < 8; ++c) acc[i][c] = 0.f;

    #pragma unroll 2
    for (int k8 = 0; k8 < K / 8; ++k8) {
        h8 av[R];
        #pragma unroll
        for (int i = 0; i < R; ++i) {
            av[i] = ((const h8*)(A + (size_t)rowc[i] * K))[k8];
        }
        #pragma unroll
        for (int kk = 0; kk < 4; ++kk) {
            int k2 = k8 * 4 + kk;
            h2 w0[4], w1[4];
            *(uint4*)w0 = *(const uint4*)(&Wl[k2 * DO + ct * 4]);
            *(uint4*)w1 = *(const uint4*)(&Wl[k2 * DO + HALF + ct * 4]);
            #pragma unroll
            for (int i = 0; i < R; ++i) {
                h2 a; a.x = av[i][2 * kk]; a.y = av[i][2 * kk + 1];
                #pragma unroll
                for (int c = 0; c < 4; ++c) {
                    acc[i][c]     = __builtin_amdgcn_fdot2(a, w0[c], acc[i][c], false);
                    acc[i][4 + c] = __builtin_amdgcn_fdot2(a, w1[c], acc[i][4 + c], false);
                }
            }
        }
    }

    #pragma unroll
    for (int i = 0; i < R; ++i) {
        int row = rb + i;
        if (row < n) {
            float dv = dinv[row];
            uint2 q0 = make_uint2(pack_h2(acc[i][0] * dv, acc[i][1] * dv),
                                  pack_h2(acc[i][2] * dv, acc[i][3] * dv));
            uint2 q1 = make_uint2(pack_h2(acc[i][4] * dv, acc[i][5] * dv),
                                  pack_h2(acc[i][6] * dv, acc[i][7] * dv));
            *(uint2*)(out + (size_t)row * DO + ct * 4) = q0;
            *(uint2*)(out + (size_t)row * DO + HALF + ct * 4) = q1;
        }
    }
}

// Plain GEMM kernel (layers 2/3).
template <int DO>
__global__ __launch_bounds__(256) void gemm16_kernel(const __half* __restrict__ A,
                                                     const float* __restrict__ W,
                                                     const float* __restrict__ dinv,
                                                     __half* __restrict__ out, int n) {
    constexpr int K = 128;
    __shared__ alignas(16) h2 Wl[(K / 2) * DO];
    gemm_tile_body<DO>(blockIdx.x, A, W, dinv, out, n, Wl);
}

// R13: fused fill_csr (blocks [0,FB)) + layer-1 GEMM (blocks [FB, FB+GB)).
// Both depend only on {scan outputs, prelude outputs}; disjoint writes.
__global__ __launch_bounds__(256) void fill_gemm1_kernel(const int* __restrict__ row,
                                                         const int* __restrict__ col,
                                                         const int* __restrict__ offsets,
                                                         int* __restrict__ cursor,
                                                         int* __restrict__ srcs, int E, int FB,
                                                         const __half* __restrict__ A,
                                                         const float* __restrict__ W,
                                                         const float* __restrict__ dinv,
                                                         __half* __restrict__ out, int n) {
    __shared__ alignas(16) h2 Wl[64 * 128];   // 32 KB (DO=128 geometry)
    int b = blockIdx.x;
    if (b < FB) {
        int e = b * 256 + threadIdx.x;
        if (e < E) {
            int c = col[e];
            int pos = offsets[c] + atomicAdd(&cursor[c], 1);
            srcs[pos] = row[e];
        }
    } else {
        gemm_tile_body<128>(b - FB, A, W, dinv, out, n, Wl);
    }
}

// out[d] = bias + dinv[d] * (hw_s[d] + sum_e hw_s[src(e)])   (f32 acc)
// TPD = DO/4 lanes/dest, 8B f16 gathers, srcs loads software-pipelined.
template <int DO, bool RELU, bool F16OUT>
__global__ __launch_bounds__(256) void agg_kernel(const __half* __restrict__ hw,
                                                  const int* __restrict__ offsets,
                                                  const int* __restrict__ srcs,
                                                  const float* __restrict__ dinv,
                                                  const float* __restrict__ bias,
                                                  void* __restrict__ outp, int n) {
    constexpr int TPD = DO / 4;            // lanes per dest
    constexpr int DPB = 256 / TPD;         // dests per block
    int d = blockIdx.x * DPB + threadIdx.x / TPD;
    int j = threadIdx.x % TPD;             // 4-col chunk index
    if (d >= n) return;

    const float2* hw2 = (const float2*)hw; // 4 halves per unit
    int beg = offsets[d];
    int end = offsets[d + 1];

    float4 acc = h4_to_f4(hw2[(size_t)d * TPD + j]);   // self term (pre-scaled)

    int e = beg;
    if (e + 8 <= end) {
        int cs[8];
        #pragma unroll
        for (int k = 0; k < 8; ++k) cs[k] = srcs[e + k];
        while (true) {
            float2 g[8];
            #pragma unroll
            for (int k = 0; k < 8; ++k) g[k] = hw2[(size_t)cs[k] * TPD + j];
            e += 8;
            bool more = (e + 8 <= end);
            int nx[8];
            if (more) {
                #pragma unroll
                for (int k = 0; k < 8; ++k) nx[k] = srcs[e + k];
            }
            #pragma unroll
            for (int k = 0; k < 8; ++k) {
                float4 f = h4_to_f4(g[k]);
                acc.x += f.x; acc.y += f.y; acc.z += f.z; acc.w += f.w;
            }
            if (!more) break;
            #pragma unroll
            for (int k = 0; k < 8; ++k) cs[k] = nx[k];
        }
    }
    for (; e + 4 <= end; e += 4) {
        int s0 = srcs[e + 0], s1 = srcs[e + 1], s2 = srcs[e + 2], s3 = srcs[e + 3];
        float4 v0 = h4_to_f4(hw2[(size_t)s0 * TPD + j]);
        float4 v1 = h4_to_f4(hw2[(size_t)s1 * TPD + j]);
        float4 v2 = h4_to_f4(hw2[(size_t)s2 * TPD + j]);
        float4 v3 = h4_to_f4(hw2[(size_t)s3 * TPD + j]);
        acc.x += v0.x; acc.y += v0.y; acc.z += v0.z; acc.w += v0.w;
        acc.x += v1.x; acc.y += v1.y; acc.z += v1.z; acc.w += v1.w;
        acc.x += v2.x; acc.y += v2.y; acc.z += v2.z; acc.w += v2.w;
        acc.x += v3.x; acc.y += v3.y; acc.z += v3.z; acc.w += v3.w;
    }
    for (; e < end; ++e) {
        float4 v = h4_to_f4(hw2[(size_t)srcs[e] * TPD + j]);
        acc.x += v.x; acc.y += v.y; acc.z += v.z; acc.w += v.w;
    }

    float di = dinv[d];
    float4 b4 = ((const float4*)bias)[j];
    acc.x = b4.x + di * acc.x;
    acc.y = b4.y + di * acc.y;
    acc.z = b4.z + di * acc.z;
    acc.w = b4.w + di * acc.w;

    if (RELU) {
        acc.x = fmaxf(acc.x, 0.f); acc.y = fmaxf(acc.y, 0.f);
        acc.z = fmaxf(acc.z, 0.f); acc.w = fmaxf(acc.w, 0.f);
    }
    if (F16OUT) {
        uint2 q = make_uint2(pack_h2(acc.x, acc.y), pack_h2(acc.z, acc.w));
        ((uint2*)outp)[(size_t)d * TPD + j] = q;
    } else {
        ((float4*)outp)[(size_t)d * TPD + j] = acc;
    }
}

extern "C" void kernel_launch(void* const* d_in, const int* in_sizes, int n_in,
                              void* d_out, int out_size, void* d_ws, size_t ws_size,
                              hipStream_t stream) {
    const float* x  = (const float*)d_in[0];
    const float* W1 = (const float*)d_in[1];
    const float* b1 = (const float*)d_in[2];
    const float* W2 = (const float*)d_in[3];
    const float* b2 = (const float*)d_in[4];
    const float* W3 = (const float*)d_in[5];
    const float* b3 = (const float*)d_in[6];
    const int*   ei = (const int*)d_in[7];

    const int N = in_sizes[0] / 128;
    const int E = in_sizes[7] / 2;
    const int* rowi = ei;       // edge_index[0] = sources
    const int* coli = ei + E;   // edge_index[1] = targets

    float* out = (float*)d_out;

    // workspace carve-up (256B aligned)
    char* ws = (char*)d_ws;
    size_t off = 0;
    auto alloc = [&](size_t bytes) -> void* {
        void* p = ws + off;
        off = (off + bytes + 255) & ~(size_t)255;
        return p;
    };
    const int NB = (N + 255) / 256;        // scan blocks (196 for N=50000)
    float* dinv     = (float*)alloc((size_t)N * 4);
    int*   counts   = (int*)  alloc(((size_t)N + 4) * 4);  // int4-padded
    int*   offsets  = (int*)  alloc((size_t)(N + 1) * 4);
    int*   cursor   = (int*)  alloc((size_t)N * 4);
    int*   aggslot  = (int*)  alloc((size_t)NB * 4);
    int*   srcs     = (int*)  alloc((size_t)E * 4);
    __half* x16     = (__half*)alloc((size_t)N * 128 * 2);
    __half* hw16    = (__half*)alloc((size_t)N * 128 * 2);
    __half* h16     = (__half*)alloc((size_t)N * 128 * 2);

    // ---- fused prelude: zero counts + init slots + x->f16 ----
    const int n4 = (N + 3) / 4;
    const int xc4 = N * 128 / 4;
    prelude_init_kernel<<<(xc4 + 255) / 256, 256, 0, stream>>>(
        (const float4*)x, (uint2*)x16, (int4*)counts, n4, aggslot, NB, xc4);
    count_edges_kernel<<<(E + 255) / 256, 256, 0, stream>>>(coli, counts, E);
    scan_fused_kernel<<<NB, 256, 0, stream>>>(counts, aggslot, offsets, cursor, dinv, N);

    // ---- fused fill_csr + layer-1 GEMM ----
    const int FB = (E + 255) / 256;            // fill blocks
    const int GB = (N + 63) / 64;              // gemm tiles
    fill_gemm1_kernel<<<FB + GB, 256, 0, stream>>>(rowi, coli, offsets, cursor, srcs, E, FB,
                                                   x16, W1, dinv, hw16, N);
    agg_kernel<128, true, true><<<(N + 7) / 8, 256, 0, stream>>>(hw16, offsets, srcs, dinv, b1, h16, N);

    // ---- layer 2 ----
    gemm16_kernel<128><<<(N + 63) / 64, 256, 0, stream>>>(h16, W2, dinv, hw16, N);
    agg_kernel<128, true, true><<<(N + 7) / 8, 256, 0, stream>>>(hw16, offsets, srcs, dinv, b2, h16, N);

    // ---- layer 3 (no relu), width 64, f32 out ----
    gemm16_kernel<64><<<(N + 63) / 64, 256, 0, stream>>>(h16, W3, dinv, hw16, N);
    agg_kernel<64, false, false><<<(N + 15) / 16, 256, 0, stream>>>(hw16, offsets, srcs, dinv, b3, out, N);
}